// Round 8
// baseline (271.393 us; speedup 1.0000x reference)
//
#include <hip/hip_runtime.h>
#include <math.h>

#define MASK_FILL_F (-987654321.0f)

typedef unsigned short u16;
typedef unsigned int   u32;

constexpr int Bb   = 64;
constexpr int Ntok = 197;
constexpr int Dim  = 768;
constexpr int Heads= 12;
constexpr int Dh   = 64;
constexpr int Nq3  = 2304;      // 3*Dim
constexpr int Rows = 12608;     // 64*197
constexpr int Mpad = 12672;     // 99*128 (ws row padding; virtual pad to 12800 is overflow-safe)

using f32x4  = __attribute__((ext_vector_type(4))) float;
using bf16x8 = __attribute__((ext_vector_type(8))) short;   // 8 bf16 (4 VGPRs)

__device__ __forceinline__ u16 f2bf(float f) {          // RNE float->bf16
  u32 u = __float_as_uint(f);
  u = (u + 0x7fffu + ((u >> 16) & 1u)) >> 16;
  return (u16)u;
}

__device__ __forceinline__ void stage16(const void* gp, void* lp) {
  __builtin_amdgcn_global_load_lds(
      (const __attribute__((address_space(1))) u32*)gp,
      (__attribute__((address_space(3))) u32*)lp, 16, 0, 0);
}

// sigma: inverse of the MFMA slot->C-row bit map (verified round 5).
__device__ __forceinline__ int sigma6(int M) {
  return (M & 0x23) | (((M >> 3) & 1) << 4) | (((M >> 2) & 1) << 3) |
         (((M >> 4) & 1) << 2);
}

// ---------------------------------------------------------------------------
// prep: fused cvt_bf16(x) + transpose_cvt(w_qkv) + transpose_cvt(w_out).
// (round-7-verified, frozen)
// ---------------------------------------------------------------------------
constexpr int NB_CVT = (Rows * Dim / 4 + 255) / 256;   // 9456
constexpr int NB_TQ  = (Nq3 / 32) * (Dim / 32);        // 1728
constexpr int NB_TO  = (Dim / 32) * (Dim / 32);        // 576

__global__ __launch_bounds__(256) void prep(
    const float* __restrict__ x, u16* __restrict__ xb,
    const float* __restrict__ w_qkv, u16* __restrict__ wqkvT,
    const float* __restrict__ w_out, u16* __restrict__ woutT)
{
  __shared__ float t[32][33];
  const int bid = blockIdx.x, tid = threadIdx.x;

  if (bid < NB_CVT) {
    const int i = bid * 256 + tid;
    if (i < Rows * Dim / 4) {
      const float4 v = *(const float4*)&x[(size_t)i * 4];
      ushort4 u;
      u.x = f2bf(v.x); u.y = f2bf(v.y); u.z = f2bf(v.z); u.w = f2bf(v.w);
      *(ushort4*)&xb[(size_t)i * 4] = u;
    }
    return;
  }

  const float* in; u16* out; int R, C, c0, r0;
  if (bid < NB_CVT + NB_TQ) {
    const int b2 = bid - NB_CVT;
    in = w_qkv; out = wqkvT; R = Dim; C = Nq3;
    c0 = (b2 % (Nq3 / 32)) * 32; r0 = (b2 / (Nq3 / 32)) * 32;
  } else {
    const int b3 = bid - NB_CVT - NB_TQ;
    in = w_out; out = woutT; R = Dim; C = Dim;
    c0 = (b3 % (Dim / 32)) * 32; r0 = (b3 / (Dim / 32)) * 32;
  }
  const int tx = tid & 31, ty = tid >> 5;
#pragma unroll
  for (int rr = ty; rr < 32; rr += 8)
    t[rr][tx] = in[(size_t)(r0 + rr) * C + c0 + tx];
  __syncthreads();
#pragma unroll
  for (int cc = ty; cc < 32; cc += 8)
    out[(size_t)(c0 + cc) * R + r0 + tx] = f2bf(t[tx][cc]);
}

// ---------------------------------------------------------------------------
// 128x128 / 4-wave / BK=64 GEMM, derived-waits 8-phase (round-2 schedule
// ported 1:1 to the half-size geometry). LDS = 64 KiB -> 2 blocks/CU (the
// round-7 256-tile ran 1 block/CU: MfmaUtil=VALUBusy=18%, all barriers
// exposed). Registers: acc 64 f32 + ~48 operand -> ~150 VGPR, fits the
// 256-cap of launch_bounds(256,2) (round-6 spill lesson respected).
//   Waves 2Mx2N; wave owns 64x64. Quadrant (MH,NH) = 32x32, 2x2 frags.
//   chunk = 8 rows x 64 cols = 1 KB; 16 chunks/matrix/tile.
//   Groups: A0 = chunks {0..3,8..11} (rows {0..31}u{64..95}), A1 = rest;
//   B likewise. Wave w stages 2 chunks of every group: A0:{w,8+w},
//   A1:{4+w,12+w}, B0:{w,8+w}, B1:{4+w,12+w} -> 2 loads/wave/phase,
//   identical positional-vmcnt(4) derivation as round 2 (proven).
//   Swizzle: slot ^= (row&7) via pre-swizzled global source (rule #21);
//   read slot = (k*4+qd)^(tx&7), row&7 == tx&7 -> 2 lanes/bank (free).
// MODE 0: rotary epilogue, bf16 C (per-element, round-5-verified math).
// MODE 1: +bias, fp32 C, row<Rows guard. Replaces BOTH gemm8p and gemm_bt1.
// ---------------------------------------------------------------------------
constexpr int Kc  = 768;
constexpr int NKT = Kc / 64;    // 12 K-tiles -> 6 iterations
#define KTC(x) ((x) < NKT ? (x) : (NKT - 1))

#define BARM() asm volatile("s_barrier" ::: "memory")
#define VMW4() asm volatile("s_waitcnt vmcnt(4)" ::: "memory")

#define STGA(chunk, kt, BUF) \
  stage16(Ag + (size_t)(m0 + (chunk) * 8 + srow) * Kc + (kt) * 64 + scol, \
          &As[BUF][(chunk) * 512])
#define STGB(chunk, kt, BUF) \
  stage16(Bg + (size_t)(n0 + (chunk) * 8 + srow) * Kc + (kt) * 64 + scol, \
          &Bs[BUF][(chunk) * 512])

#define RDA(BUF, MH) \
  _Pragma("unroll") for (int m_ = 0; m_ < 2; ++m_) \
  _Pragma("unroll") for (int k_ = 0; k_ < 2; ++k_) \
    af[m_][k_] = *(const bf16x8*)&As[BUF][(wr * 64 + (MH) * 32 + m_ * 16 + tx) * 64 \
                                          + (((k_ * 4 + qd) ^ sx) * 8)];
#define RDB(BUF, NH, BFR) \
  _Pragma("unroll") for (int n_ = 0; n_ < 2; ++n_) \
  _Pragma("unroll") for (int k_ = 0; k_ < 2; ++k_) \
    BFR[n_][k_] = *(const bf16x8*)&Bs[BUF][(wc * 64 + (NH) * 32 + n_ * 16 + tx) * 64 \
                                           + (((k_ * 4 + qd) ^ sx) * 8)];

#define MM(MH, NH, BFR) \
  __builtin_amdgcn_s_setprio(1); \
  _Pragma("unroll") for (int m_ = 0; m_ < 2; ++m_) \
  _Pragma("unroll") for (int n_ = 0; n_ < 2; ++n_) \
  _Pragma("unroll") for (int k_ = 0; k_ < 2; ++k_) \
    acc[(MH) * 2 + m_][(NH) * 2 + n_] = __builtin_amdgcn_mfma_f32_16x16x32_bf16( \
        af[m_][k_], BFR[n_][k_], acc[(MH) * 2 + m_][(NH) * 2 + n_], 0, 0, 0); \
  __builtin_amdgcn_s_setprio(0);

template<int MODE, int TN>
__global__ __launch_bounds__(256, 2) void gemm128(
    const u16* __restrict__ Ag, const u16* __restrict__ Bg,
    void* __restrict__ Cv, int Nn, int nwg,
    const float* __restrict__ pe, const float* __restrict__ bias)
{
  __shared__ u16 As[2][128 * 64];   // 32 KiB (A dbuf)
  __shared__ u16 Bs[2][128 * 64];   // 32 KiB (B dbuf) -> 64 KiB total

  const int tid = threadIdx.x, lane = tid & 63, w = tid >> 6;   // w in 0..3

  // T1: bijective XCD swizzle (m204 formula); 1800%8==0, 600%8==0
  const int orig = blockIdx.x;
  const int q8 = nwg >> 3, r8 = nwg & 7;
  const int xcd = orig & 7, sub = orig >> 3;
  const int wgid = (xcd < r8 ? xcd * (q8 + 1) : r8 * (q8 + 1) + (xcd - r8) * q8) + sub;
  const int tm = wgid / TN, tn = wgid % TN;
  const int m0 = tm * 128, n0 = tn * 128;

  const int wr = w >> 1, wc = w & 1;               // 2M x 2N waves
  const int tx = lane & 15, qd = lane >> 4, sx = tx & 7;

  // staging: chunk = 8 rows x 64 cols, linear LDS dest, pre-swizzled source
  const int srow = lane >> 3;
  const int scol = ((lane & 7) ^ srow) * 8;

  // ---- prologue: tile0 (all 4 groups) + tile1 (A0,B1), steady order ----
  STGA(w, 0, 0);       STGA(8 + w, 0, 0);        // A0(0)
  STGB(4 + w, 0, 0);   STGB(12 + w, 0, 0);       // B1(0)
  STGA(4 + w, 0, 0);   STGA(12 + w, 0, 0);       // A1(0)
  STGB(w, 0, 0);       STGB(8 + w, 0, 0);        // B0(0)
  STGA(w, 1, 1);       STGA(8 + w, 1, 1);        // A0(1)
  STGB(4 + w, 1, 1);   STGB(12 + w, 1, 1);       // B1(1)
  VMW4();              // tile0 fully resident; A0(1),B1(1) in flight
  BARM();

  f32x4  acc[4][4] = {};
  bf16x8 af[2][2], bf0[2][2], bf1[2][2];

#pragma unroll 1
  for (int i = 0; i < NKT / 2; ++i) {
    const int u = 2 * i;
    // ph0: Q(00) tile u | stage A1(u+1)->buf1
    RDA(0, 0); RDB(0, 0, bf0);
    STGA(4 + w, u + 1, 1); STGA(12 + w, u + 1, 1);
    BARM(); MM(0, 0, bf0); BARM();
    // ph1: Q(01) | stage B0(u+1)->buf1
    RDB(0, 1, bf1);
    STGB(w, u + 1, 1); STGB(8 + w, u + 1, 1);
    BARM(); MM(0, 1, bf1); BARM();
    // ph2: Q(11) | stage A0(u+2)->buf0
    RDA(0, 1);
    STGA(w, KTC(u + 2), 0); STGA(8 + w, KTC(u + 2), 0);
    BARM(); MM(1, 1, bf1); BARM();
    // ph3: Q(10) (register reuse) | stage B1(u+2)->buf0 | vmcnt(4)
    STGB(4 + w, KTC(u + 2), 0); STGB(12 + w, KTC(u + 2), 0);
    BARM(); MM(1, 0, bf0); VMW4(); BARM();
    // ph4: Q(00) tile u+1 | stage A1(u+2)->buf0
    RDA(1, 0); RDB(1, 0, bf0);
    STGA(4 + w, KTC(u + 2), 0); STGA(12 + w, KTC(u + 2), 0);
    BARM(); MM(0, 0, bf0); BARM();
    // ph5: Q(01) | stage B0(u+2)->buf0
    RDB(1, 1, bf1);
    STGB(w, KTC(u + 2), 0); STGB(8 + w, KTC(u + 2), 0);
    BARM(); MM(0, 1, bf1); BARM();
    // ph6: Q(11) | stage A0(u+3)->buf1
    RDA(1, 1);
    STGA(w, KTC(u + 3), 1); STGA(8 + w, KTC(u + 3), 1);
    BARM(); MM(1, 1, bf1); BARM();
    // ph7: Q(10) (register reuse) | stage B1(u+3)->buf1 | vmcnt(4)
    STGB(4 + w, KTC(u + 3), 1); STGB(12 + w, KTC(u + 3), 1);
    BARM(); MM(1, 0, bf0); VMW4(); BARM();
  }

  // ---- epilogue ----
  if (MODE == 0) {
    u16* Cb = (u16*)Cv;
    const bool dorot = (n0 < 2 * Dim);
#pragma unroll
    for (int mi = 0; mi < 4; ++mi) {
      const int rbase = m0 + wr * 64 + mi * 16 + qd * 4;
      int iq[4];
#pragma unroll
      for (int r = 0; r < 4; ++r) iq[r] = (rbase + r) % Ntok;
#pragma unroll
      for (int ni = 0; ni < 4; ++ni) {
        const int col = n0 + wc * 64 + ni * 16 + tx;
        const int mm  = (col & 63) >> 1;
        const int odd = col & 1;
#pragma unroll
        for (int r = 0; r < 4; ++r) {
          float v = acc[mi][ni][r];
          float res = v;
          if (dorot) {
            const float other = __shfl_xor(v, 1, 64);
            const float sn = pe[iq[r] * 64 + mm];
            const float c2 = pe[iq[r] * 64 + 32 + mm];
            res = odd ? (v * c2 + other * sn) : (v * c2 - other * sn);
          }
          Cb[(size_t)(rbase + r) * Nn + col] = f2bf(res);
        }
      }
    }
  } else {
    float* C = (float*)Cv;
#pragma unroll
    for (int mi = 0; mi < 4; ++mi) {
      const int rbase = m0 + wr * 64 + mi * 16 + qd * 4;
#pragma unroll
      for (int ni = 0; ni < 4; ++ni) {
        const int col = n0 + wc * 64 + ni * 16 + tx;
        const float bv = bias[col];
#pragma unroll
        for (int r = 0; r < 4; ++r) {
          const int row = rbase + r;
          if (row < Rows) C[(size_t)row * Nn + col] = acc[mi][ni][r] + bv;
        }
      }
    }
  }
}

// ---------------------------------------------------------------------------
// MFMA flash attention v10 (attn16f): round-7-verified, FROZEN.
// ---------------------------------------------------------------------------
constexpr int LS = 72;

__global__ __launch_bounds__(1024) void attn16(
    const u16* __restrict__ qkvB,
    const float* __restrict__ scale, u16* __restrict__ outB)
{
  __shared__ u16 ks  [64 * LS];   // K [sigma-permuted j][d]
  __shared__ u16 vtmp[64 * LS];   // V [j][d]  (raw rows)
  __shared__ u16 vts [64 * LS];   // V^T[d][j]

  const int bh = blockIdx.x;
  const int b = bh / Heads, h = bh % Heads;
  const float sc = scale[h];
  const int tid = threadIdx.x, lane = tid & 63, w = tid >> 6;   // w in 0..15
  const int tx = lane & 15, q = lane >> 4;
  const size_t rowbase = (size_t)b * Ntok;
  const bool active = (w < 13);

  // stage slot: tid<512 -> K row sigma6(Ms); tid>=512 -> V row jr=Ms
  const int Ms = (tid & 511) >> 3, c8s = (tid & 7) * 8;
  const bool isK = tid < 512;
  const u16* kgp = qkvB + (rowbase + sigma6(Ms)) * (size_t)Nq3 + Dim + h * Dh + c8s;
  const u16* vgp = qkvB + (rowbase + Ms) * (size_t)Nq3 + 2 * Dim + h * Dh + c8s;
  u16* slds = (isK ? ks : vtmp) + Ms * LS + c8s;

  // transpose slot for tid<512: d = tid&63, j8 = tid>>6
  const int td = tid & 63, tj8 = (tid & 511) >> 6;

  // ---- Q fragments straight to registers (row 16w+tx) ----
  bf16x8 bq[2];
  if (active) {
#pragma unroll
    for (int kk = 0; kk < 2; ++kk)
      bq[kk] = *(const bf16x8*)(qkvB +
          (rowbase + 16 * w + tx) * (size_t)Nq3 + h * Dh + kk * 32 + q * 8);
  }

  // tile 0 in flight (T14); tile-0 V rows (0..63) all < Ntok: no guard
  uint4 sreg = isK ? *(const uint4*)kgp : *(const uint4*)vgp;

  float l_part = 0.f;                   // per-lane partial sum of p
  f32x4 oacc[4] = {};                   // O[i = 16w+4q+r][d = nb*16+tx]

  for (int jt = 0; jt < 4; ++jt) {
    const int j0 = jt * 64;
    __syncthreads();                    // bar0: prev tile's ks/vts reads done
    *(uint4*)slds = sreg;               // K->ks or V-row->vtmp
    __syncthreads();                    // bar1: vtmp/ks resident

    if (!isK) {
      if (jt < 3) {                     // V prefetch, zero-guarded tail
        const int j = (jt + 1) * 64 + Ms;
        sreg = (j < Ntok) ? *(const uint4*)(vgp + (size_t)(jt + 1) * 64 * Nq3)
                          : make_uint4(0u, 0u, 0u, 0u);
      }
    } else {
      // LDS transpose vtmp -> vts (exact vtrans gather; d=td, cols tj8*8..+7)
      ushort4 lo, hi;
      lo.x = vtmp[(tj8 * 8 + 0) * LS + td]; lo.y = vtmp[(tj8 * 8 + 1) * LS + td];
      lo.z = vtmp[(tj8 * 8 + 2) * LS + td]; lo.w = vtmp[(tj8 * 8 + 3) * LS + td];
      hi.x = vtmp[(tj8 * 8 + 4) * LS + td]; hi.y = vtmp[(tj8 * 8 + 5) * LS + td];
      hi.z = vtmp[(tj8 * 8 + 6) * LS + td]; hi.w = vtmp[(tj8 * 8 + 7) * LS + td];
      *(ushort4*)&vts[td * LS + tj8 * 8]     = lo;
      *(ushort4*)&vts[td * LS + tj8 * 8 + 4] = hi;
      if (jt < 3)                       // K prefetch (garbage rows masked by p=0)
        sreg = *(const uint4*)(kgp + (size_t)(jt + 1) * 64 * Nq3);
    }
    __syncthreads();                    // bar2: vts built

    if (active) {
      // ---- S^T = K(sigma)·Q^T ----
      f32x4 sT[4] = {};
      __builtin_amdgcn_s_setprio(1);
#pragma unroll
      for (int kk = 0; kk < 2; ++kk)
#pragma unroll
        for (int jb = 0; jb < 4; ++jb) {
          const bf16x8 ka = *(const bf16x8*)&ks[(jb * 16 + tx) * LS + kk * 32 + q * 8];
          sT[jb] = __builtin_amdgcn_mfma_f32_16x16x32_bf16(ka, bq[kk], sT[jb], 0, 0, 0);
        }
      __builtin_amdgcn_s_setprio(0);

      // ---- single-pass: p = exp(s*sc), masked; pack P for PV ----
      const int ig = 16 * w + tx;
      union { bf16x8 v; u16 e[8]; } pk[2];
      float lp = 0.f;
#pragma unroll
      for (int jb = 0; jb < 4; ++jb)
#pragma unroll
        for (int r = 0; r < 4; ++r) {
          const int jg = j0 + 32 * (jb >> 1) + 8 * q + 4 * (jb & 1) + r;
          const float s = fminf(sT[jb][r] * sc, 80.f);
          const bool bad = (jg >= Ntok) || (jg == ig);
          const float p = bad ? 0.f : __expf(s);
          lp += p;
          pk[jb >> 1].e[(jb & 1) * 4 + r] = f2bf(p);
        }
      l_part += lp;

      // ---- O += P·V ----
      __builtin_amdgcn_s_setprio(1);
#pragma unroll
      for (int kk = 0; kk < 2; ++kk)
#pragma unroll
        for (int nb = 0; nb < 4; ++nb) {
          const bf16x8 vb = *(const bf16x8*)&vts[(nb * 16 + tx) * LS + kk * 32 + q * 8];
          oacc[nb] = __builtin_amdgcn_mfma_f32_16x16x32_bf16(pk[kk].v, vb,
                                                            oacc[nb], 0, 0, 0);
        }
      __builtin_amdgcn_s_setprio(0);
    }
  }

  // ---- epilogue: reduce l over quads, normalize, per-element stores ----
  if (active) {
    float l = l_part;
    l += __shfl_xor(l, 16, 64);
    l += __shfl_xor(l, 32, 64);      // row total (row = tx within this wave)
    const float linv = 1.0f / l;
#pragma unroll
    for (int r = 0; r < 4; ++r) {
      const float lr = __shfl(linv, 4 * q + r, 64);
      const int igr = 16 * w + 4 * q + r;
      if (igr < Ntok) {
#pragma unroll
        for (int nb = 0; nb < 4; ++nb)
          outB[(rowbase + igr) * (size_t)Dim + h * Dh + nb * 16 + tx] =
              f2bf(oacc[nb][r] * lr);
      }
    }
  }
}

// ---------------------------------------------------------------------------
extern "C" void kernel_launch(void* const* d_in, const int* in_sizes, int n_in,
                              void* d_out, int out_size, void* d_ws, size_t ws_size,
                              hipStream_t stream) {
  const float* x     = (const float*)d_in[0];
  const float* pe    = (const float*)d_in[1];
  const float* w_qkv = (const float*)d_in[2];
  const float* scale = (const float*)d_in[3];
  const float* w_out = (const float*)d_in[4];
  const float* b_out = (const float*)d_in[5];
  float* out = (float*)d_out;

  u16* xb    = (u16*)d_ws;                       // [Mpad][768]
  u16* wqkvT = xb    + (size_t)Mpad * Dim;       // [2304][768]
  u16* woutT = wqkvT + (size_t)Nq3 * Dim;        // [768][768]
  u16* qkvB  = woutT + (size_t)Dim * Dim;        // [Mpad][2304]
  u16* attnB = qkvB  + (size_t)Mpad * Nq3;       // [Mpad][768]
  // (old vT region stays allocated; absorbs virtual-pad overflow reads)

  prep<<<NB_CVT + NB_TQ + NB_TO, 256, 0, stream>>>(x, xb, w_qkv, wqkvT, w_out, woutT);

  // QKV GEMM: M(virt)=12800 -> 100 row-tiles, N=2304 -> 18 col-tiles
  constexpr int NWG0 = 100 * 18;
  gemm128<0, 18><<<NWG0, 256, 0, stream>>>(xb, wqkvT, qkvB, Nq3, NWG0, pe, nullptr);

  attn16<<<Bb * Heads, 1024, 0, stream>>>(qkvB, scale, attnB);

  // out GEMM: M(virt)=12800 -> 100 row-tiles, N=768 -> 6 col-tiles
  constexpr int NWG1 = 100 * 6;
  gemm128<1, 6><<<NWG1, 256, 0, stream>>>(attnB, woutT, out, Dim, NWG1, nullptr, b_out);
}

// Round 10
// 255.853 us; speedup vs baseline: 1.0607x; 1.0607x over previous
//
#include <hip/hip_runtime.h>
#include <math.h>

#define MASK_FILL_F (-987654321.0f)

typedef unsigned short u16;
typedef unsigned int   u32;

constexpr int Bb   = 64;
constexpr int Ntok = 197;
constexpr int Dim  = 768;
constexpr int Heads= 12;
constexpr int Dh   = 64;
constexpr int Nq3  = 2304;      // 3*Dim
constexpr int Rows = 12608;     // 64*197
constexpr int Mpad = 12672;     // 99*128 (ws row padding; virtual pad to 12800 is overflow-safe)

using f32x4  = __attribute__((ext_vector_type(4))) float;
using bf16x8 = __attribute__((ext_vector_type(8))) short;   // 8 bf16 (4 VGPRs)

__device__ __forceinline__ u16 f2bf(float f) {          // RNE float->bf16
  u32 u = __float_as_uint(f);
  u = (u + 0x7fffu + ((u >> 16) & 1u)) >> 16;
  return (u16)u;
}

__device__ __forceinline__ void stage16(const void* gp, void* lp) {
  __builtin_amdgcn_global_load_lds(
      (const __attribute__((address_space(1))) u32*)gp,
      (__attribute__((address_space(3))) u32*)lp, 16, 0, 0);
}

// sigma: inverse of the MFMA slot->C-row bit map (verified round 5).
__device__ __forceinline__ int sigma6(int M) {
  return (M & 0x23) | (((M >> 3) & 1) << 4) | (((M >> 2) & 1) << 3) |
         (((M >> 4) & 1) << 2);
}

// ---------------------------------------------------------------------------
// prep: fused cvt_bf16(x) + transpose_cvt(w_qkv) + transpose_cvt(w_out).
// (round-7-verified, frozen)
// ---------------------------------------------------------------------------
constexpr int NB_CVT = (Rows * Dim / 4 + 255) / 256;   // 9456
constexpr int NB_TQ  = (Nq3 / 32) * (Dim / 32);        // 1728
constexpr int NB_TO  = (Dim / 32) * (Dim / 32);        // 576

__global__ __launch_bounds__(256) void prep(
    const float* __restrict__ x, u16* __restrict__ xb,
    const float* __restrict__ w_qkv, u16* __restrict__ wqkvT,
    const float* __restrict__ w_out, u16* __restrict__ woutT)
{
  __shared__ float t[32][33];
  const int bid = blockIdx.x, tid = threadIdx.x;

  if (bid < NB_CVT) {
    const int i = bid * 256 + tid;
    if (i < Rows * Dim / 4) {
      const float4 v = *(const float4*)&x[(size_t)i * 4];
      ushort4 u;
      u.x = f2bf(v.x); u.y = f2bf(v.y); u.z = f2bf(v.z); u.w = f2bf(v.w);
      *(ushort4*)&xb[(size_t)i * 4] = u;
    }
    return;
  }

  const float* in; u16* out; int R, C, c0, r0;
  if (bid < NB_CVT + NB_TQ) {
    const int b2 = bid - NB_CVT;
    in = w_qkv; out = wqkvT; R = Dim; C = Nq3;
    c0 = (b2 % (Nq3 / 32)) * 32; r0 = (b2 / (Nq3 / 32)) * 32;
  } else {
    const int b3 = bid - NB_CVT - NB_TQ;
    in = w_out; out = woutT; R = Dim; C = Dim;
    c0 = (b3 % (Dim / 32)) * 32; r0 = (b3 / (Dim / 32)) * 32;
  }
  const int tx = tid & 31, ty = tid >> 5;
#pragma unroll
  for (int rr = ty; rr < 32; rr += 8)
    t[rr][tx] = in[(size_t)(r0 + rr) * C + c0 + tx];
  __syncthreads();
#pragma unroll
  for (int cc = ty; cc < 32; cc += 8)
    out[(size_t)(c0 + cc) * R + r0 + tx] = f2bf(t[tx][cc]);
}

// ---------------------------------------------------------------------------
// 256x256 / 8-wave / BK=64 GEMM — round-2 derived-waits schedule with the
// 8 phases MERGED INTO 4: two quadrants per phase, same ds_reads / staging
// slots / positional vmcnt(4), barriers halved 96 -> 48.
// Safety audit (round-10 resubmit after infra failure):
//   - all 512 threads execute every s_barrier (no divergent barrier);
//   - every staged region's last ds_read completes before the barrier that
//     precedes its stage (checked for all 8 group x buffer targets);
//   - VMW4 at mph1 end leaves only mph1's 4 loads outstanding -> covers
//     mph2's buf1 reads; VMW4 at mph3 end covers next mph0's buf0 reads.
// Per-accumulator MFMA order unchanged -> bit-identical output.
// Tests: barrier-convoy-bound (expect -10..-20us) vs latency-bound (0).
// ---------------------------------------------------------------------------
constexpr int Kc  = 768;
constexpr int NKT = Kc / 64;    // 12 K-tiles -> 6 iterations
#define KTC(x) ((x) < NKT ? (x) : (NKT - 1))

#define BARM() asm volatile("s_barrier" ::: "memory")
#define VMW4() asm volatile("s_waitcnt vmcnt(4)" ::: "memory")

#define STGA(chunk, kt, BUF) \
  stage16(Ag + (size_t)(m0 + (chunk) * 8 + srow) * Kc + (kt) * 64 + scol, \
          &As[BUF][(chunk) * 512])
#define STGB(chunk, kt, BUF) \
  stage16(Bg + (size_t)(n0 + (chunk) * 8 + srow) * Kc + (kt) * 64 + scol, \
          &Bs[BUF][(chunk) * 512])

#define RDA(BUF, MH) \
  _Pragma("unroll") for (int m_ = 0; m_ < 4; ++m_) \
  _Pragma("unroll") for (int k_ = 0; k_ < 2; ++k_) \
    af[m_][k_] = *(const bf16x8*)&As[BUF][(wr * 128 + (MH) * 64 + m_ * 16 + tx) * 64 \
                                          + (((k_ * 4 + qd) ^ sx) * 8)];
#define RDB(BUF, NH, BFR) \
  _Pragma("unroll") for (int n_ = 0; n_ < 2; ++n_) \
  _Pragma("unroll") for (int k_ = 0; k_ < 2; ++k_) \
    BFR[n_][k_] = *(const bf16x8*)&Bs[BUF][(wc * 64 + (NH) * 32 + n_ * 16 + tx) * 64 \
                                           + (((k_ * 4 + qd) ^ sx) * 8)];

#define MM(MH, NH, BFR) \
  __builtin_amdgcn_s_setprio(1); \
  _Pragma("unroll") for (int m_ = 0; m_ < 4; ++m_) \
  _Pragma("unroll") for (int n_ = 0; n_ < 2; ++n_) \
  _Pragma("unroll") for (int k_ = 0; k_ < 2; ++k_) \
    acc[(MH) * 4 + m_][(NH) * 2 + n_] = __builtin_amdgcn_mfma_f32_16x16x32_bf16( \
        af[m_][k_], BFR[n_][k_], acc[(MH) * 4 + m_][(NH) * 2 + n_], 0, 0, 0); \
  __builtin_amdgcn_s_setprio(0);

template<int TN>
__global__ __launch_bounds__(512, 2) void gemm8p(
    const u16* __restrict__ Ag, const u16* __restrict__ Bg,
    u16* __restrict__ Cb, int Nn, int nwg,
    const float* __restrict__ pe)
{
  __shared__ u16 As[2][256 * 64];   // 128 KiB total with Bs
  __shared__ u16 Bs[2][256 * 64];

  const int tid = threadIdx.x, lane = tid & 63, w = tid >> 6;

  // T1: bijective XCD swizzle (m204 formula)
  const int orig = blockIdx.x;
  const int q8 = nwg >> 3, r8 = nwg & 7;
  const int xcd = orig & 7, sub = orig >> 3;
  const int wgid = (xcd < r8 ? xcd * (q8 + 1) : r8 * (q8 + 1) + (xcd - r8) * q8) + sub;
  const int tm = wgid / TN, tn = wgid % TN;
  const int m0 = tm * 256, n0 = tn * 256;

  const int wr = w >> 2, wc = w & 3;               // 2M x 4N waves
  const int tx = lane & 15, qd = lane >> 4, sx = tx & 7;

  // staging geometry: chunk = 8 rows x 64 cols (1024 B), linear LDS dest,
  // pre-swizzled global source: lane l -> row 8c+(l>>3), colgrp (l&7)^(l>>3)
  const int srow = lane >> 3;
  const int scol = ((lane & 7) ^ srow) * 8;
  const int b0 = (w >> 1) * 8 + (w & 1) * 2;

  // ---- prologue: tile0 (all 4 groups) + tile1 (A0,B1), steady order ----
  STGA(w, 0, 0);        STGA(16 + w, 0, 0);       // A0(0)
  STGB(b0 + 4, 0, 0);   STGB(b0 + 5, 0, 0);       // B1(0)
  STGA(8 + w, 0, 0);    STGA(24 + w, 0, 0);       // A1(0)
  STGB(b0, 0, 0);       STGB(b0 + 1, 0, 0);       // B0(0)
  STGA(w, 1, 1);        STGA(16 + w, 1, 1);       // A0(1)
  STGB(b0 + 4, 1, 1);   STGB(b0 + 5, 1, 1);       // B1(1)
  VMW4();               // tile0 fully resident; A0(1),B1(1) in flight
  BARM();

  f32x4  acc[8][4] = {};
  bf16x8 af[4][2], bf0[2][2], bf1[2][2];

#pragma unroll 1
  for (int i = 0; i < NKT / 2; ++i) {
    const int u = 2 * i;
    // mph0 (= old ph0+ph1): tile u quadrants (0,0),(0,1)
    //   stage A1(u+1)->buf1, B0(u+1)->buf1
    RDA(0, 0); RDB(0, 0, bf0); RDB(0, 1, bf1);
    STGA(8 + w, u + 1, 1); STGA(24 + w, u + 1, 1);
    STGB(b0, u + 1, 1);    STGB(b0 + 1, u + 1, 1);
    BARM(); MM(0, 0, bf0); MM(0, 1, bf1); BARM();
    // mph1 (= old ph2+ph3): quadrants (1,1),(1,0) (bf reg reuse)
    //   stage A0(u+2)->buf0, B1(u+2)->buf0 | vmcnt(4)
    RDA(0, 1);
    STGA(w, KTC(u + 2), 0);      STGA(16 + w, KTC(u + 2), 0);
    STGB(b0 + 4, KTC(u + 2), 0); STGB(b0 + 5, KTC(u + 2), 0);
    BARM(); MM(1, 1, bf1); MM(1, 0, bf0); VMW4(); BARM();
    // mph2 (= old ph4+ph5): tile u+1 quadrants (0,0),(0,1)
    //   stage A1(u+2)->buf0, B0(u+2)->buf0
    RDA(1, 0); RDB(1, 0, bf0); RDB(1, 1, bf1);
    STGA(8 + w, KTC(u + 2), 0); STGA(24 + w, KTC(u + 2), 0);
    STGB(b0, KTC(u + 2), 0);    STGB(b0 + 1, KTC(u + 2), 0);
    BARM(); MM(0, 0, bf0); MM(0, 1, bf1); BARM();
    // mph3 (= old ph6+ph7): quadrants (1,1),(1,0)
    //   stage A0(u+3)->buf1, B1(u+3)->buf1 | vmcnt(4)
    RDA(1, 1);
    STGA(w, KTC(u + 3), 1);      STGA(16 + w, KTC(u + 3), 1);
    STGB(b0 + 4, KTC(u + 3), 1); STGB(b0 + 5, KTC(u + 3), 1);
    BARM(); MM(1, 1, bf1); MM(1, 0, bf0); VMW4(); BARM();
  }

  // ---- epilogue: rotary (Q/K cols) or plain (V cols), bf16 stores ----
  const bool dorot = (n0 < 2 * Dim);
#pragma unroll
  for (int mi = 0; mi < 8; ++mi) {
    const int rbase = m0 + wr * 128 + mi * 16 + qd * 4;
    int iq[4];
#pragma unroll
    for (int r = 0; r < 4; ++r) iq[r] = (rbase + r) % Ntok;
#pragma unroll
    for (int ni = 0; ni < 4; ++ni) {
      const int col = n0 + wc * 64 + ni * 16 + tx;
      const int mm  = (col & 63) >> 1;
      const int odd = col & 1;
#pragma unroll
      for (int r = 0; r < 4; ++r) {
        float v = acc[mi][ni][r];
        float res = v;
        if (dorot) {
          const float other = __shfl_xor(v, 1, 64);
          const float sn = pe[iq[r] * 64 + mm];
          const float c2 = pe[iq[r] * 64 + 32 + mm];
          res = odd ? (v * c2 + other * sn) : (v * c2 - other * sn);
        }
        Cb[(size_t)(rbase + r) * Nn + col] = f2bf(res);
      }
    }
  }
}

// ---------------------------------------------------------------------------
// m97-style 128x128 / BK=32 GEMM for the output projection (round-0-verified
// MODE-1 path, verbatim): +bias, fp32 C, row guard. 594 blocks.
// ---------------------------------------------------------------------------
__global__ __launch_bounds__(256) void gemm_bt1(
    const u16* __restrict__ Ag, const u16* __restrict__ Bg,
    float* __restrict__ C, int K, int Nn, const float* __restrict__ bias)
{
  __shared__ u16 As[128 * 32];
  __shared__ u16 Bs[128 * 32];
  const int tid = threadIdx.x, lane = tid & 63, w = tid >> 6;
  const int m0 = blockIdx.y * 128, n0 = blockIdx.x * 128;
  const int wm = (w & 1) * 64, wn = (w >> 1) * 64;
  const int tx = lane & 15, qk = lane >> 4;
  const int rs = lane >> 2, cs = (lane & 3) * 8;

  f32x4 acc[4][4] = {};

  for (int k0 = 0; k0 < K; k0 += 32) {
#pragma unroll
    for (int t = 0; t < 2; ++t) {
      const int r0 = w * 16 + t * 64;
      stage16(Ag + (size_t)(m0 + r0 + rs) * K + k0 + cs, &As[r0 * 32]);
      stage16(Bg + (size_t)(n0 + r0 + rs) * K + k0 + cs, &Bs[r0 * 32]);
    }
    __syncthreads();
    bf16x8 af[4], bf[4];
#pragma unroll
    for (int f = 0; f < 4; ++f) {
      af[f] = *(const bf16x8*)&As[(wm + f * 16 + tx) * 32 + qk * 8];
      bf[f] = *(const bf16x8*)&Bs[(wn + f * 16 + tx) * 32 + qk * 8];
    }
#pragma unroll
    for (int fm = 0; fm < 4; ++fm)
#pragma unroll
      for (int fn = 0; fn < 4; ++fn)
        acc[fm][fn] = __builtin_amdgcn_mfma_f32_16x16x32_bf16(
            af[fm], bf[fn], acc[fm][fn], 0, 0, 0);
    __syncthreads();
  }

#pragma unroll
  for (int fm = 0; fm < 4; ++fm) {
    const int rbase = m0 + wm + fm * 16 + qk * 4;
#pragma unroll
    for (int fn = 0; fn < 4; ++fn) {
      const int col = n0 + wn + fn * 16 + tx;
      const float bv = bias[col];
#pragma unroll
      for (int r = 0; r < 4; ++r) {
        const int row = rbase + r;
        if (row < Rows) C[(size_t)row * Nn + col] = acc[fm][fn][r] + bv;
      }
    }
  }
}

// ---------------------------------------------------------------------------
// MFMA flash attention v10 (attn16f): round-7-verified, FROZEN.
// ---------------------------------------------------------------------------
constexpr int LS = 72;

__global__ __launch_bounds__(1024) void attn16(
    const u16* __restrict__ qkvB,
    const float* __restrict__ scale, u16* __restrict__ outB)
{
  __shared__ u16 ks  [64 * LS];   // K [sigma-permuted j][d]
  __shared__ u16 vtmp[64 * LS];   // V [j][d]  (raw rows)
  __shared__ u16 vts [64 * LS];   // V^T[d][j]

  const int bh = blockIdx.x;
  const int b = bh / Heads, h = bh % Heads;
  const float sc = scale[h];
  const int tid = threadIdx.x, lane = tid & 63, w = tid >> 6;   // w in 0..15
  const int tx = lane & 15, q = lane >> 4;
  const size_t rowbase = (size_t)b * Ntok;
  const bool active = (w < 13);

  // stage slot: tid<512 -> K row sigma6(Ms); tid>=512 -> V row jr=Ms
  const int Ms = (tid & 511) >> 3, c8s = (tid & 7) * 8;
  const bool isK = tid < 512;
  const u16* kgp = qkvB + (rowbase + sigma6(Ms)) * (size_t)Nq3 + Dim + h * Dh + c8s;
  const u16* vgp = qkvB + (rowbase + Ms) * (size_t)Nq3 + 2 * Dim + h * Dh + c8s;
  u16* slds = (isK ? ks : vtmp) + Ms * LS + c8s;

  // transpose slot for tid<512: d = tid&63, j8 = tid>>6
  const int td = tid & 63, tj8 = (tid & 511) >> 6;

  // ---- Q fragments straight to registers (row 16w+tx) ----
  bf16x8 bq[2];
  if (active) {
#pragma unroll
    for (int kk = 0; kk < 2; ++kk)
      bq[kk] = *(const bf16x8*)(qkvB +
          (rowbase + 16 * w + tx) * (size_t)Nq3 + h * Dh + kk * 32 + q * 8);
  }

  // tile 0 in flight (T14); tile-0 V rows (0..63) all < Ntok: no guard
  uint4 sreg = isK ? *(const uint4*)kgp : *(const uint4*)vgp;

  float l_part = 0.f;                   // per-lane partial sum of p
  f32x4 oacc[4] = {};                   // O[i = 16w+4q+r][d = nb*16+tx]

  for (int jt = 0; jt < 4; ++jt) {
    const int j0 = jt * 64;
    __syncthreads();                    // bar0: prev tile's ks/vts reads done
    *(uint4*)slds = sreg;               // K->ks or V-row->vtmp
    __syncthreads();                    // bar1: vtmp/ks resident

    if (!isK) {
      if (jt < 3) {                     // V prefetch, zero-guarded tail
        const int j = (jt + 1) * 64 + Ms;
        sreg = (j < Ntok) ? *(const uint4*)(vgp + (size_t)(jt + 1) * 64 * Nq3)
                          : make_uint4(0u, 0u, 0u, 0u);
      }
    } else {
      // LDS transpose vtmp -> vts (exact vtrans gather; d=td, cols tj8*8..+7)
      ushort4 lo, hi;
      lo.x = vtmp[(tj8 * 8 + 0) * LS + td]; lo.y = vtmp[(tj8 * 8 + 1) * LS + td];
      lo.z = vtmp[(tj8 * 8 + 2) * LS + td]; lo.w = vtmp[(tj8 * 8 + 3) * LS + td];
      hi.x = vtmp[(tj8 * 8 + 4) * LS + td]; hi.y = vtmp[(tj8 * 8 + 5) * LS + td];
      hi.z = vtmp[(tj8 * 8 + 6) * LS + td]; hi.w = vtmp[(tj8 * 8 + 7) * LS + td];
      *(ushort4*)&vts[td * LS + tj8 * 8]     = lo;
      *(ushort4*)&vts[td * LS + tj8 * 8 + 4] = hi;
      if (jt < 3)                       // K prefetch (garbage rows masked by p=0)
        sreg = *(const uint4*)(kgp + (size_t)(jt + 1) * 64 * Nq3);
    }
    __syncthreads();                    // bar2: vts built

    if (active) {
      // ---- S^T = K(sigma)·Q^T ----
      f32x4 sT[4] = {};
      __builtin_amdgcn_s_setprio(1);
#pragma unroll
      for (int kk = 0; kk < 2; ++kk)
#pragma unroll
        for (int jb = 0; jb < 4; ++jb) {
          const bf16x8 ka = *(const bf16x8*)&ks[(jb * 16 + tx) * LS + kk * 32 + q * 8];
          sT[jb] = __builtin_amdgcn_mfma_f32_16x16x32_bf16(ka, bq[kk], sT[jb], 0, 0, 0);
        }
      __builtin_amdgcn_s_setprio(0);

      // ---- single-pass: p = exp(s*sc), masked; pack P for PV ----
      const int ig = 16 * w + tx;
      union { bf16x8 v; u16 e[8]; } pk[2];
      float lp = 0.f;
#pragma unroll
      for (int jb = 0; jb < 4; ++jb)
#pragma unroll
        for (int r = 0; r < 4; ++r) {
          const int jg = j0 + 32 * (jb >> 1) + 8 * q + 4 * (jb & 1) + r;
          const float s = fminf(sT[jb][r] * sc, 80.f);
          const bool bad = (jg >= Ntok) || (jg == ig);
          const float p = bad ? 0.f : __expf(s);
          lp += p;
          pk[jb >> 1].e[(jb & 1) * 4 + r] = f2bf(p);
        }
      l_part += lp;

      // ---- O += P·V ----
      __builtin_amdgcn_s_setprio(1);
#pragma unroll
      for (int kk = 0; kk < 2; ++kk)
#pragma unroll
        for (int nb = 0; nb < 4; ++nb) {
          const bf16x8 vb = *(const bf16x8*)&vts[(nb * 16 + tx) * LS + kk * 32 + q * 8];
          oacc[nb] = __builtin_amdgcn_mfma_f32_16x16x32_bf16(pk[kk].v, vb,
                                                            oacc[nb], 0, 0, 0);
        }
      __builtin_amdgcn_s_setprio(0);
    }
  }

  // ---- epilogue: reduce l over quads, normalize, per-element stores ----
  if (active) {
    float l = l_part;
    l += __shfl_xor(l, 16, 64);
    l += __shfl_xor(l, 32, 64);      // row total (row = tx within this wave)
    const float linv = 1.0f / l;
#pragma unroll
    for (int r = 0; r < 4; ++r) {
      const float lr = __shfl(linv, 4 * q + r, 64);
      const int igr = 16 * w + 4 * q + r;
      if (igr < Ntok) {
#pragma unroll
        for (int nb = 0; nb < 4; ++nb)
          outB[(rowbase + igr) * (size_t)Dim + h * Dh + nb * 16 + tx] =
              f2bf(oacc[nb][r] * lr);
      }
    }
  }
}

// ---------------------------------------------------------------------------
extern "C" void kernel_launch(void* const* d_in, const int* in_sizes, int n_in,
                              void* d_out, int out_size, void* d_ws, size_t ws_size,
                              hipStream_t stream) {
  const float* x     = (const float*)d_in[0];
  const float* pe    = (const float*)d_in[1];
  const float* w_qkv = (const float*)d_in[2];
  const float* scale = (const float*)d_in[3];
  const float* w_out = (const float*)d_in[4];
  const float* b_out = (const float*)d_in[5];
  float* out = (float*)d_out;

  u16* xb    = (u16*)d_ws;                       // [Mpad][768]
  u16* wqkvT = xb    + (size_t)Mpad * Dim;       // [2304][768]
  u16* woutT = wqkvT + (size_t)Nq3 * Dim;        // [768][768]
  u16* qkvB  = woutT + (size_t)Dim * Dim;        // [Mpad][2304]
  u16* attnB = qkvB  + (size_t)Mpad * Nq3;       // [Mpad][768]
  // (old vT region stays allocated; absorbs virtual-pad overflow reads)

  prep<<<NB_CVT + NB_TQ + NB_TO, 256, 0, stream>>>(x, xb, w_qkv, wqkvT, w_out, woutT);

  // QKV GEMM: M(virt)=12800 -> 50 row-tiles, N=2304 -> 9 col-tiles
  constexpr int NWG0 = 50 * 9;
  gemm8p<9><<<NWG0, 512, 0, stream>>>(xb, wqkvT, qkvB, Nq3, NWG0, pe);

  attn16<<<Bb * Heads, 1024, 0, stream>>>(qkvB, scale, attnB);

  // out GEMM: 128x128 tiles, 6x99 = 594 blocks
  gemm_bt1<<<dim3(Dim / 128, Mpad / 128), 256, 0, stream>>>(
      attnB, woutT, out, Dim, Dim, b_out);
}

// Round 11
// 254.545 us; speedup vs baseline: 1.0662x; 1.0051x over previous
//
#include <hip/hip_runtime.h>
#include <math.h>

#define MASK_FILL_F (-987654321.0f)

typedef unsigned short u16;
typedef unsigned int   u32;

constexpr int Bb   = 64;
constexpr int Ntok = 197;
constexpr int Dim  = 768;
constexpr int Heads= 12;
constexpr int Dh   = 64;
constexpr int Nq3  = 2304;      // 3*Dim
constexpr int Rows = 12608;     // 64*197
constexpr int Mpad = 12672;     // 99*128 (ws row padding; virtual pad to 12800 is overflow-safe)

using f32x4  = __attribute__((ext_vector_type(4))) float;
using bf16x8 = __attribute__((ext_vector_type(8))) short;   // 8 bf16 (4 VGPRs)

__device__ __forceinline__ u16 f2bf(float f) {          // RNE float->bf16
  u32 u = __float_as_uint(f);
  u = (u + 0x7fffu + ((u >> 16) & 1u)) >> 16;
  return (u16)u;
}

__device__ __forceinline__ void stage16(const void* gp, void* lp) {
  __builtin_amdgcn_global_load_lds(
      (const __attribute__((address_space(1))) u32*)gp,
      (__attribute__((address_space(3))) u32*)lp, 16, 0, 0);
}

// sigma: inverse of the MFMA slot->C-row bit map (verified round 5).
__device__ __forceinline__ int sigma6(int M) {
  return (M & 0x23) | (((M >> 3) & 1) << 4) | (((M >> 2) & 1) << 3) |
         (((M >> 4) & 1) << 2);
}

// ---------------------------------------------------------------------------
// prep: fused cvt_bf16(x) + transpose_cvt(w_qkv) + transpose_cvt(w_out).
// (round-7-verified, frozen)
// ---------------------------------------------------------------------------
constexpr int NB_CVT = (Rows * Dim / 4 + 255) / 256;   // 9456
constexpr int NB_TQ  = (Nq3 / 32) * (Dim / 32);        // 1728
constexpr int NB_TO  = (Dim / 32) * (Dim / 32);        // 576

__global__ __launch_bounds__(256) void prep(
    const float* __restrict__ x, u16* __restrict__ xb,
    const float* __restrict__ w_qkv, u16* __restrict__ wqkvT,
    const float* __restrict__ w_out, u16* __restrict__ woutT)
{
  __shared__ float t[32][33];
  const int bid = blockIdx.x, tid = threadIdx.x;

  if (bid < NB_CVT) {
    const int i = bid * 256 + tid;
    if (i < Rows * Dim / 4) {
      const float4 v = *(const float4*)&x[(size_t)i * 4];
      ushort4 u;
      u.x = f2bf(v.x); u.y = f2bf(v.y); u.z = f2bf(v.z); u.w = f2bf(v.w);
      *(ushort4*)&xb[(size_t)i * 4] = u;
    }
    return;
  }

  const float* in; u16* out; int R, C, c0, r0;
  if (bid < NB_CVT + NB_TQ) {
    const int b2 = bid - NB_CVT;
    in = w_qkv; out = wqkvT; R = Dim; C = Nq3;
    c0 = (b2 % (Nq3 / 32)) * 32; r0 = (b2 / (Nq3 / 32)) * 32;
  } else {
    const int b3 = bid - NB_CVT - NB_TQ;
    in = w_out; out = woutT; R = Dim; C = Dim;
    c0 = (b3 % (Dim / 32)) * 32; r0 = (b3 / (Dim / 32)) * 32;
  }
  const int tx = tid & 31, ty = tid >> 5;
#pragma unroll
  for (int rr = ty; rr < 32; rr += 8)
    t[rr][tx] = in[(size_t)(r0 + rr) * C + c0 + tx];
  __syncthreads();
#pragma unroll
  for (int cc = ty; cc < 32; cc += 8)
    out[(size_t)(c0 + cc) * R + r0 + tx] = f2bf(t[tx][cc]);
}

// ---------------------------------------------------------------------------
// 256x256 / 8-wave / BK=64 GEMM — merged-4-phase schedule (round-10, -6.3us
// verified) with barriers further halved 48 -> 24 (round-11): ONE barrier
// per phase, preceded by s_waitcnt lgkmcnt(0).
// Safety (re-proved for 1-barrier layout, all 8 group x buffer targets):
//   - read-before-overwrite: each phase's ds_reads are lgkmcnt(0)-drained
//     BEFORE its barrier; every overwriting stage executes after all waves
//     pass that barrier (>=1 barrier separation incl. loop boundary).
//   - write-before-read: positional VMW4 at mph1/mph3 ends, BEFORE the
//     barrier -> cross-wave staging visibility identical to round 10
//     (outstanding <=12 -> 4, same counts).
//   - memory ops can't cross "memory"-clobber asm -> per-wave program-order
//     vmcnt counting holds; MFMA order unchanged -> bit-identical output.
// ---------------------------------------------------------------------------
constexpr int Kc  = 768;
constexpr int NKT = Kc / 64;    // 12 K-tiles -> 6 iterations
#define KTC(x) ((x) < NKT ? (x) : (NKT - 1))

#define BARM()  asm volatile("s_barrier" ::: "memory")
#define VMW4()  asm volatile("s_waitcnt vmcnt(4)" ::: "memory")
#define LGKM0() asm volatile("s_waitcnt lgkmcnt(0)" ::: "memory")

#define STGA(chunk, kt, BUF) \
  stage16(Ag + (size_t)(m0 + (chunk) * 8 + srow) * Kc + (kt) * 64 + scol, \
          &As[BUF][(chunk) * 512])
#define STGB(chunk, kt, BUF) \
  stage16(Bg + (size_t)(n0 + (chunk) * 8 + srow) * Kc + (kt) * 64 + scol, \
          &Bs[BUF][(chunk) * 512])

#define RDA(BUF, MH) \
  _Pragma("unroll") for (int m_ = 0; m_ < 4; ++m_) \
  _Pragma("unroll") for (int k_ = 0; k_ < 2; ++k_) \
    af[m_][k_] = *(const bf16x8*)&As[BUF][(wr * 128 + (MH) * 64 + m_ * 16 + tx) * 64 \
                                          + (((k_ * 4 + qd) ^ sx) * 8)];
#define RDB(BUF, NH, BFR) \
  _Pragma("unroll") for (int n_ = 0; n_ < 2; ++n_) \
  _Pragma("unroll") for (int k_ = 0; k_ < 2; ++k_) \
    BFR[n_][k_] = *(const bf16x8*)&Bs[BUF][(wc * 64 + (NH) * 32 + n_ * 16 + tx) * 64 \
                                           + (((k_ * 4 + qd) ^ sx) * 8)];

#define MM(MH, NH, BFR) \
  __builtin_amdgcn_s_setprio(1); \
  _Pragma("unroll") for (int m_ = 0; m_ < 4; ++m_) \
  _Pragma("unroll") for (int n_ = 0; n_ < 2; ++n_) \
  _Pragma("unroll") for (int k_ = 0; k_ < 2; ++k_) \
    acc[(MH) * 4 + m_][(NH) * 2 + n_] = __builtin_amdgcn_mfma_f32_16x16x32_bf16( \
        af[m_][k_], BFR[n_][k_], acc[(MH) * 4 + m_][(NH) * 2 + n_], 0, 0, 0); \
  __builtin_amdgcn_s_setprio(0);

template<int TN>
__global__ __launch_bounds__(512, 2) void gemm8p(
    const u16* __restrict__ Ag, const u16* __restrict__ Bg,
    u16* __restrict__ Cb, int Nn, int nwg,
    const float* __restrict__ pe)
{
  __shared__ u16 As[2][256 * 64];   // 128 KiB total with Bs
  __shared__ u16 Bs[2][256 * 64];

  const int tid = threadIdx.x, lane = tid & 63, w = tid >> 6;

  // T1: bijective XCD swizzle (m204 formula)
  const int orig = blockIdx.x;
  const int q8 = nwg >> 3, r8 = nwg & 7;
  const int xcd = orig & 7, sub = orig >> 3;
  const int wgid = (xcd < r8 ? xcd * (q8 + 1) : r8 * (q8 + 1) + (xcd - r8) * q8) + sub;
  const int tm = wgid / TN, tn = wgid % TN;
  const int m0 = tm * 256, n0 = tn * 256;

  const int wr = w >> 2, wc = w & 3;               // 2M x 4N waves
  const int tx = lane & 15, qd = lane >> 4, sx = tx & 7;

  // staging geometry: chunk = 8 rows x 64 cols (1024 B), linear LDS dest,
  // pre-swizzled global source: lane l -> row 8c+(l>>3), colgrp (l&7)^(l>>3)
  const int srow = lane >> 3;
  const int scol = ((lane & 7) ^ srow) * 8;
  const int b0 = (w >> 1) * 8 + (w & 1) * 2;

  // ---- prologue: tile0 (all 4 groups) + tile1 (A0,B1), steady order ----
  STGA(w, 0, 0);        STGA(16 + w, 0, 0);       // A0(0)
  STGB(b0 + 4, 0, 0);   STGB(b0 + 5, 0, 0);       // B1(0)
  STGA(8 + w, 0, 0);    STGA(24 + w, 0, 0);       // A1(0)
  STGB(b0, 0, 0);       STGB(b0 + 1, 0, 0);       // B0(0)
  STGA(w, 1, 1);        STGA(16 + w, 1, 1);       // A0(1)
  STGB(b0 + 4, 1, 1);   STGB(b0 + 5, 1, 1);       // B1(1)
  VMW4();               // tile0 fully resident; A0(1),B1(1) in flight
  BARM();

  f32x4  acc[8][4] = {};
  bf16x8 af[4][2], bf0[2][2], bf1[2][2];

#pragma unroll 1
  for (int i = 0; i < NKT / 2; ++i) {
    const int u = 2 * i;
    // mph0: tile u quadrants (0,0),(0,1) | stage A1(u+1),B0(u+1)->buf1
    RDA(0, 0); RDB(0, 0, bf0); RDB(0, 1, bf1);
    STGA(8 + w, u + 1, 1); STGA(24 + w, u + 1, 1);
    STGB(b0, u + 1, 1);    STGB(b0 + 1, u + 1, 1);
    LGKM0(); BARM();
    MM(0, 0, bf0); MM(0, 1, bf1);
    // mph1: quadrants (1,1),(1,0) (bf reg reuse)
    //   stage A0(u+2),B1(u+2)->buf0 | vmcnt(4) before barrier
    RDA(0, 1);
    STGA(w, KTC(u + 2), 0);      STGA(16 + w, KTC(u + 2), 0);
    STGB(b0 + 4, KTC(u + 2), 0); STGB(b0 + 5, KTC(u + 2), 0);
    LGKM0(); VMW4(); BARM();
    MM(1, 1, bf1); MM(1, 0, bf0);
    // mph2: tile u+1 quadrants (0,0),(0,1) | stage A1(u+2),B0(u+2)->buf0
    RDA(1, 0); RDB(1, 0, bf0); RDB(1, 1, bf1);
    STGA(8 + w, KTC(u + 2), 0); STGA(24 + w, KTC(u + 2), 0);
    STGB(b0, KTC(u + 2), 0);    STGB(b0 + 1, KTC(u + 2), 0);
    LGKM0(); BARM();
    MM(0, 0, bf0); MM(0, 1, bf1);
    // mph3: quadrants (1,1),(1,0)
    //   stage A0(u+3),B1(u+3)->buf1 | vmcnt(4) before barrier
    RDA(1, 1);
    STGA(w, KTC(u + 3), 1);      STGA(16 + w, KTC(u + 3), 1);
    STGB(b0 + 4, KTC(u + 3), 1); STGB(b0 + 5, KTC(u + 3), 1);
    LGKM0(); VMW4(); BARM();
    MM(1, 1, bf1); MM(1, 0, bf0);
  }

  // ---- epilogue: rotary (Q/K cols) or plain (V cols), bf16 stores ----
  const bool dorot = (n0 < 2 * Dim);
#pragma unroll
  for (int mi = 0; mi < 8; ++mi) {
    const int rbase = m0 + wr * 128 + mi * 16 + qd * 4;
    int iq[4];
#pragma unroll
    for (int r = 0; r < 4; ++r) iq[r] = (rbase + r) % Ntok;
#pragma unroll
    for (int ni = 0; ni < 4; ++ni) {
      const int col = n0 + wc * 64 + ni * 16 + tx;
      const int mm  = (col & 63) >> 1;
      const int odd = col & 1;
#pragma unroll
      for (int r = 0; r < 4; ++r) {
        float v = acc[mi][ni][r];
        float res = v;
        if (dorot) {
          const float other = __shfl_xor(v, 1, 64);
          const float sn = pe[iq[r] * 64 + mm];
          const float c2 = pe[iq[r] * 64 + 32 + mm];
          res = odd ? (v * c2 + other * sn) : (v * c2 - other * sn);
        }
        Cb[(size_t)(rbase + r) * Nn + col] = f2bf(res);
      }
    }
  }
}

// ---------------------------------------------------------------------------
// m97-style 128x128 / BK=32 GEMM for the output projection (round-0-verified
// MODE-1 path, verbatim): +bias, fp32 C, row guard. 594 blocks. FROZEN.
// ---------------------------------------------------------------------------
__global__ __launch_bounds__(256) void gemm_bt1(
    const u16* __restrict__ Ag, const u16* __restrict__ Bg,
    float* __restrict__ C, int K, int Nn, const float* __restrict__ bias)
{
  __shared__ u16 As[128 * 32];
  __shared__ u16 Bs[128 * 32];
  const int tid = threadIdx.x, lane = tid & 63, w = tid >> 6;
  const int m0 = blockIdx.y * 128, n0 = blockIdx.x * 128;
  const int wm = (w & 1) * 64, wn = (w >> 1) * 64;
  const int tx = lane & 15, qk = lane >> 4;
  const int rs = lane >> 2, cs = (lane & 3) * 8;

  f32x4 acc[4][4] = {};

  for (int k0 = 0; k0 < K; k0 += 32) {
#pragma unroll
    for (int t = 0; t < 2; ++t) {
      const int r0 = w * 16 + t * 64;
      stage16(Ag + (size_t)(m0 + r0 + rs) * K + k0 + cs, &As[r0 * 32]);
      stage16(Bg + (size_t)(n0 + r0 + rs) * K + k0 + cs, &Bs[r0 * 32]);
    }
    __syncthreads();
    bf16x8 af[4], bf[4];
#pragma unroll
    for (int f = 0; f < 4; ++f) {
      af[f] = *(const bf16x8*)&As[(wm + f * 16 + tx) * 32 + qk * 8];
      bf[f] = *(const bf16x8*)&Bs[(wn + f * 16 + tx) * 32 + qk * 8];
    }
#pragma unroll
    for (int fm = 0; fm < 4; ++fm)
#pragma unroll
      for (int fn = 0; fn < 4; ++fn)
        acc[fm][fn] = __builtin_amdgcn_mfma_f32_16x16x32_bf16(
            af[fm], bf[fn], acc[fm][fn], 0, 0, 0);
    __syncthreads();
  }

#pragma unroll
  for (int fm = 0; fm < 4; ++fm) {
    const int rbase = m0 + wm + fm * 16 + qk * 4;
#pragma unroll
    for (int fn = 0; fn < 4; ++fn) {
      const int col = n0 + wn + fn * 16 + tx;
      const float bv = bias[col];
#pragma unroll
      for (int r = 0; r < 4; ++r) {
        const int row = rbase + r;
        if (row < Rows) C[(size_t)row * Nn + col] = acc[fm][fn][r] + bv;
      }
    }
  }
}

// ---------------------------------------------------------------------------
// MFMA flash attention v10 (attn16f): round-7-verified, FROZEN.
// ---------------------------------------------------------------------------
constexpr int LS = 72;

__global__ __launch_bounds__(1024) void attn16(
    const u16* __restrict__ qkvB,
    const float* __restrict__ scale, u16* __restrict__ outB)
{
  __shared__ u16 ks  [64 * LS];   // K [sigma-permuted j][d]
  __shared__ u16 vtmp[64 * LS];   // V [j][d]  (raw rows)
  __shared__ u16 vts [64 * LS];   // V^T[d][j]

  const int bh = blockIdx.x;
  const int b = bh / Heads, h = bh % Heads;
  const float sc = scale[h];
  const int tid = threadIdx.x, lane = tid & 63, w = tid >> 6;   // w in 0..15
  const int tx = lane & 15, q = lane >> 4;
  const size_t rowbase = (size_t)b * Ntok;
  const bool active = (w < 13);

  // stage slot: tid<512 -> K row sigma6(Ms); tid>=512 -> V row jr=Ms
  const int Ms = (tid & 511) >> 3, c8s = (tid & 7) * 8;
  const bool isK = tid < 512;
  const u16* kgp = qkvB + (rowbase + sigma6(Ms)) * (size_t)Nq3 + Dim + h * Dh + c8s;
  const u16* vgp = qkvB + (rowbase + Ms) * (size_t)Nq3 + 2 * Dim + h * Dh + c8s;
  u16* slds = (isK ? ks : vtmp) + Ms * LS + c8s;

  // transpose slot for tid<512: d = tid&63, j8 = tid>>6
  const int td = tid & 63, tj8 = (tid & 511) >> 6;

  // ---- Q fragments straight to registers (row 16w+tx) ----
  bf16x8 bq[2];
  if (active) {
#pragma unroll
    for (int kk = 0; kk < 2; ++kk)
      bq[kk] = *(const bf16x8*)(qkvB +
          (rowbase + 16 * w + tx) * (size_t)Nq3 + h * Dh + kk * 32 + q * 8);
  }

  // tile 0 in flight (T14); tile-0 V rows (0..63) all < Ntok: no guard
  uint4 sreg = isK ? *(const uint4*)kgp : *(const uint4*)vgp;

  float l_part = 0.f;                   // per-lane partial sum of p
  f32x4 oacc[4] = {};                   // O[i = 16w+4q+r][d = nb*16+tx]

  for (int jt = 0; jt < 4; ++jt) {
    const int j0 = jt * 64;
    __syncthreads();                    // bar0: prev tile's ks/vts reads done
    *(uint4*)slds = sreg;               // K->ks or V-row->vtmp
    __syncthreads();                    // bar1: vtmp/ks resident

    if (!isK) {
      if (jt < 3) {                     // V prefetch, zero-guarded tail
        const int j = (jt + 1) * 64 + Ms;
        sreg = (j < Ntok) ? *(const uint4*)(vgp + (size_t)(jt + 1) * 64 * Nq3)
                          : make_uint4(0u, 0u, 0u, 0u);
      }
    } else {
      // LDS transpose vtmp -> vts (exact vtrans gather; d=td, cols tj8*8..+7)
      ushort4 lo, hi;
      lo.x = vtmp[(tj8 * 8 + 0) * LS + td]; lo.y = vtmp[(tj8 * 8 + 1) * LS + td];
      lo.z = vtmp[(tj8 * 8 + 2) * LS + td]; lo.w = vtmp[(tj8 * 8 + 3) * LS + td];
      hi.x = vtmp[(tj8 * 8 + 4) * LS + td]; hi.y = vtmp[(tj8 * 8 + 5) * LS + td];
      hi.z = vtmp[(tj8 * 8 + 6) * LS + td]; hi.w = vtmp[(tj8 * 8 + 7) * LS + td];
      *(ushort4*)&vts[td * LS + tj8 * 8]     = lo;
      *(ushort4*)&vts[td * LS + tj8 * 8 + 4] = hi;
      if (jt < 3)                       // K prefetch (garbage rows masked by p=0)
        sreg = *(const uint4*)(kgp + (size_t)(jt + 1) * 64 * Nq3);
    }
    __syncthreads();                    // bar2: vts built

    if (active) {
      // ---- S^T = K(sigma)·Q^T ----
      f32x4 sT[4] = {};
      __builtin_amdgcn_s_setprio(1);
#pragma unroll
      for (int kk = 0; kk < 2; ++kk)
#pragma unroll
        for (int jb = 0; jb < 4; ++jb) {
          const bf16x8 ka = *(const bf16x8*)&ks[(jb * 16 + tx) * LS + kk * 32 + q * 8];
          sT[jb] = __builtin_amdgcn_mfma_f32_16x16x32_bf16(ka, bq[kk], sT[jb], 0, 0, 0);
        }
      __builtin_amdgcn_s_setprio(0);

      // ---- single-pass: p = exp(s*sc), masked; pack P for PV ----
      const int ig = 16 * w + tx;
      union { bf16x8 v; u16 e[8]; } pk[2];
      float lp = 0.f;
#pragma unroll
      for (int jb = 0; jb < 4; ++jb)
#pragma unroll
        for (int r = 0; r < 4; ++r) {
          const int jg = j0 + 32 * (jb >> 1) + 8 * q + 4 * (jb & 1) + r;
          const float s = fminf(sT[jb][r] * sc, 80.f);
          const bool bad = (jg >= Ntok) || (jg == ig);
          const float p = bad ? 0.f : __expf(s);
          lp += p;
          pk[jb >> 1].e[(jb & 1) * 4 + r] = f2bf(p);
        }
      l_part += lp;

      // ---- O += P·V ----
      __builtin_amdgcn_s_setprio(1);
#pragma unroll
      for (int kk = 0; kk < 2; ++kk)
#pragma unroll
        for (int nb = 0; nb < 4; ++nb) {
          const bf16x8 vb = *(const bf16x8*)&vts[(nb * 16 + tx) * LS + kk * 32 + q * 8];
          oacc[nb] = __builtin_amdgcn_mfma_f32_16x16x32_bf16(pk[kk].v, vb,
                                                            oacc[nb], 0, 0, 0);
        }
      __builtin_amdgcn_s_setprio(0);
    }
  }

  // ---- epilogue: reduce l over quads, normalize, per-element stores ----
  if (active) {
    float l = l_part;
    l += __shfl_xor(l, 16, 64);
    l += __shfl_xor(l, 32, 64);      // row total (row = tx within this wave)
    const float linv = 1.0f / l;
#pragma unroll
    for (int r = 0; r < 4; ++r) {
      const float lr = __shfl(linv, 4 * q + r, 64);
      const int igr = 16 * w + 4 * q + r;
      if (igr < Ntok) {
#pragma unroll
        for (int nb = 0; nb < 4; ++nb)
          outB[(rowbase + igr) * (size_t)Dim + h * Dh + nb * 16 + tx] =
              f2bf(oacc[nb][r] * lr);
      }
    }
  }
}

// ---------------------------------------------------------------------------
extern "C" void kernel_launch(void* const* d_in, const int* in_sizes, int n_in,
                              void* d_out, int out_size, void* d_ws, size_t ws_size,
                              hipStream_t stream) {
  const float* x     = (const float*)d_in[0];
  const float* pe    = (const float*)d_in[1];
  const float* w_qkv = (const float*)d_in[2];
  const float* scale = (const float*)d_in[3];
  const float* w_out = (const float*)d_in[4];
  const float* b_out = (const float*)d_in[5];
  float* out = (float*)d_out;

  u16* xb    = (u16*)d_ws;                       // [Mpad][768]
  u16* wqkvT = xb    + (size_t)Mpad * Dim;       // [2304][768]
  u16* woutT = wqkvT + (size_t)Nq3 * Dim;        // [768][768]
  u16* qkvB  = woutT + (size_t)Dim * Dim;        // [Mpad][2304]
  u16* attnB = qkvB  + (size_t)Mpad * Nq3;       // [Mpad][768]
  // (old vT region stays allocated; absorbs virtual-pad overflow reads)

  prep<<<NB_CVT + NB_TQ + NB_TO, 256, 0, stream>>>(x, xb, w_qkv, wqkvT, w_out, woutT);

  // QKV GEMM: M(virt)=12800 -> 50 row-tiles, N=2304 -> 9 col-tiles
  constexpr int NWG0 = 50 * 9;
  gemm8p<9><<<NWG0, 512, 0, stream>>>(xb, wqkvT, qkvB, Nq3, NWG0, pe);

  attn16<<<Bb * Heads, 1024, 0, stream>>>(qkvB, scale, attnB);

  // out GEMM: 128x128 tiles, 6x99 = 594 blocks
  gemm_bt1<<<dim3(Dim / 128, Mpad / 128), 256, 0, stream>>>(
      attnB, woutT, out, Dim, Dim, b_out);
}